// Round 6
// baseline (250.793 us; speedup 1.0000x reference)
//
#include <hip/hip_runtime.h>
#include <float.h>

#define NUM_Q 8192
#define NUM_P 4096

typedef float  f32x4 __attribute__((ext_vector_type(4)));
typedef int    i32x4 __attribute__((ext_vector_type(4)));

// One block (256 threads = 4 waves) per TWO adjacent rows -> 64 KB contiguous
// stream per block (32 KB pred + 32 KB y). All 16 NT loads issued up-front
// (256 B/thread in flight). Single barrier (row-min broadcast); per-wave hinge
// partials go straight to ws[row*4+wave] so no second barrier is needed.
__global__ __launch_bounds__(256)
void mmrl_kernel(const float* __restrict__ pred,
                 const int* __restrict__ y,
                 float* __restrict__ ws) {
    const int row0 = blockIdx.x * 2;          // rows row0, row0+1
    const int t    = threadIdx.x;
    const int wave = t >> 6;
    const int lane = t & 63;

    const f32x4* p0 = reinterpret_cast<const f32x4*>(pred + (size_t)row0 * NUM_P);
    const i32x4* y0 = reinterpret_cast<const i32x4*>(y    + (size_t)row0 * NUM_P);
    // row1 streams are contiguous continuations (+1024 vectors)

    // ---- issue everything: y (mask needed first), then pred ----
    i32x4 yv[8];
#pragma unroll
    for (int i = 0; i < 4; ++i) yv[i]     = __builtin_nontemporal_load(&y0[t + 256 * i]);
#pragma unroll
    for (int i = 0; i < 4; ++i) yv[4 + i] = __builtin_nontemporal_load(&y0[1024 + t + 256 * i]);
    f32x4 pv[8];
#pragma unroll
    for (int i = 0; i < 4; ++i) pv[i]     = __builtin_nontemporal_load(&p0[t + 256 * i]);
#pragma unroll
    for (int i = 0; i < 4; ++i) pv[4 + i] = __builtin_nontemporal_load(&p0[1024 + t + 256 * i]);

    // ---- relevance masks (waits only on y loads) ----
    unsigned int m0 = 0u, m1 = 0u;
#pragma unroll
    for (int i = 0; i < 4; ++i) {
        m0 |= ((unsigned int)(yv[i].x == 1)     ) << (4 * i);
        m0 |= ((unsigned int)(yv[i].y == 1) << 1) << (4 * i);
        m0 |= ((unsigned int)(yv[i].z == 1) << 2) << (4 * i);
        m0 |= ((unsigned int)(yv[i].w == 1) << 3) << (4 * i);
        m1 |= ((unsigned int)(yv[4 + i].x == 1)     ) << (4 * i);
        m1 |= ((unsigned int)(yv[4 + i].y == 1) << 1) << (4 * i);
        m1 |= ((unsigned int)(yv[4 + i].z == 1) << 2) << (4 * i);
        m1 |= ((unsigned int)(yv[4 + i].w == 1) << 3) << (4 * i);
    }

    // ---- Phase 1: masked min, two independent chains (ILP) ----
    float lmin0 = FLT_MAX, lmin1 = FLT_MAX;
#pragma unroll
    for (int i = 0; i < 4; ++i) {
        lmin0 = fminf(lmin0, (m0 & (1u << (4 * i))) ? pv[i].x : FLT_MAX);
        lmin0 = fminf(lmin0, (m0 & (2u << (4 * i))) ? pv[i].y : FLT_MAX);
        lmin0 = fminf(lmin0, (m0 & (4u << (4 * i))) ? pv[i].z : FLT_MAX);
        lmin0 = fminf(lmin0, (m0 & (8u << (4 * i))) ? pv[i].w : FLT_MAX);
        lmin1 = fminf(lmin1, (m1 & (1u << (4 * i))) ? pv[4 + i].x : FLT_MAX);
        lmin1 = fminf(lmin1, (m1 & (2u << (4 * i))) ? pv[4 + i].y : FLT_MAX);
        lmin1 = fminf(lmin1, (m1 & (4u << (4 * i))) ? pv[4 + i].z : FLT_MAX);
        lmin1 = fminf(lmin1, (m1 & (8u << (4 * i))) ? pv[4 + i].w : FLT_MAX);
    }
#pragma unroll
    for (int off = 32; off > 0; off >>= 1) {
        lmin0 = fminf(lmin0, __shfl_xor(lmin0, off));
        lmin1 = fminf(lmin1, __shfl_xor(lmin1, off));
    }

    __shared__ float smin[2][4];
    if (lane == 0) { smin[0][wave] = lmin0; smin[1][wave] = lmin1; }
    __syncthreads();
    const float rmin0 = fminf(fminf(smin[0][0], smin[0][1]), fminf(smin[0][2], smin[0][3]));
    const float rmin1 = fminf(fminf(smin[1][0], smin[1][1]), fminf(smin[1][2], smin[1][3]));

    // ---- Phase 2: hinge sums, two chains; per-wave partial to ws ----
    float lsum0 = 0.0f, lsum1 = 0.0f;
#pragma unroll
    for (int i = 0; i < 4; ++i) {
        lsum0 += (m0 & (1u << (4 * i))) ? 0.0f : fmaxf(pv[i].x - rmin0, 0.0f);
        lsum0 += (m0 & (2u << (4 * i))) ? 0.0f : fmaxf(pv[i].y - rmin0, 0.0f);
        lsum0 += (m0 & (4u << (4 * i))) ? 0.0f : fmaxf(pv[i].z - rmin0, 0.0f);
        lsum0 += (m0 & (8u << (4 * i))) ? 0.0f : fmaxf(pv[i].w - rmin0, 0.0f);
        lsum1 += (m1 & (1u << (4 * i))) ? 0.0f : fmaxf(pv[4 + i].x - rmin1, 0.0f);
        lsum1 += (m1 & (2u << (4 * i))) ? 0.0f : fmaxf(pv[4 + i].y - rmin1, 0.0f);
        lsum1 += (m1 & (4u << (4 * i))) ? 0.0f : fmaxf(pv[4 + i].z - rmin1, 0.0f);
        lsum1 += (m1 & (8u << (4 * i))) ? 0.0f : fmaxf(pv[4 + i].w - rmin1, 0.0f);
    }
#pragma unroll
    for (int off = 32; off > 0; off >>= 1) {
        lsum0 += __shfl_xor(lsum0, off);
        lsum1 += __shfl_xor(lsum1, off);
    }

    if (lane == 0) {
        ws[(size_t)row0 * 4 + wave]       = lsum0;   // per-wave partials,
        ws[(size_t)(row0 + 1) * 4 + wave] = lsum1;   // no second barrier
    }
}

// Single-block reduction over 8192 rows x 4 wave-partials = 32768 floats.
__global__ __launch_bounds__(256)
void mmrl_reduce_kernel(const float* __restrict__ partial,
                        float* __restrict__ out) {
    const int t = threadIdx.x;
    const f32x4* p4 = reinterpret_cast<const f32x4*>(partial);
    float s = 0.0f;
#pragma unroll
    for (int i = 0; i < 32; ++i) {  // 256 threads * 32 f32x4 = 32768 floats
        f32x4 v = p4[t + 256 * i];
        s += (v.x + v.y) + (v.z + v.w);
    }
#pragma unroll
    for (int off = 32; off > 0; off >>= 1)
        s += __shfl_xor(s, off);

    __shared__ float ss[4];
    if ((t & 63) == 0) ss[t >> 6] = s;
    __syncthreads();

    if (t == 0) {
        const float total = (ss[0] + ss[1]) + (ss[2] + ss[3]);
        // mean over Q*P = 2^25 — exact power-of-two scale
        out[0] = total * (1.0f / ((float)NUM_Q * (float)NUM_P));
    }
}

extern "C" void kernel_launch(void* const* d_in, const int* in_sizes, int n_in,
                              void* d_out, int out_size, void* d_ws, size_t ws_size,
                              hipStream_t stream) {
    const float* pred = (const float*)d_in[0];
    const int*   y    = (const int*)d_in[1];
    float* out = (float*)d_out;
    float* ws  = (float*)d_ws;  // 32768 floats = 128 KB scratch

    mmrl_kernel<<<NUM_Q / 2, 256, 0, stream>>>(pred, y, ws);
    mmrl_reduce_kernel<<<1, 256, 0, stream>>>(ws, out);
}